// Round 4
// baseline (235.969 us; speedup 1.0000x reference)
//
#include <hip/hip_runtime.h>

// ElectronGNN on MI355X (gfx950).  Inputs float32, output float32.
// One block per batch element (512 blocks, 256 threads = 4 waves).
// Barrier-minimal design (~8 __syncthreads per block, was ~228):
//  - z-GEMM B-frags recomputed per lane: x[j][d] (LDS u16) * we[f][d] (regs, v_pk_mul_f16)
//  - weight-GEMM B-frags read directly from global (L2-resident wupT/ywT)
//  - z C->A transpose via zst touches only the wave's own 16 rows (no barrier)
//  - distances per-lane in registers (no dee/dne LDS, kills 16-way bank conflicts)
// MFMA: v_mfma_f32_16x16x32_f16, fp32 accum; x residual fp32 in C-layout regs.

typedef unsigned short u16;
typedef unsigned int u32;
typedef __attribute__((ext_vector_type(8))) short short8;
typedef __attribute__((ext_vector_type(4))) float f32x4;
typedef __attribute__((ext_vector_type(4))) u32 u32x4;
typedef _Float16 h2 __attribute__((ext_vector_type(2)));

__device__ __forceinline__ u16 f2h(float f){ return __builtin_bit_cast(u16, (_Float16)f); }
__device__ __forceinline__ float h2f(u16 a){ return (float)__builtin_bit_cast(_Float16, a); }

// 8 Gaussian RBF features of distance dd, fp16-packed.
__device__ __forceinline__ short8 rbf8(float dd){
  short8 a;
#pragma unroll
  for (int f = 0; f < 8; f++){
    float u = dd - (4.0f/7.0f)*(float)f;
    a[f] = (short)f2h(__expf(-u*u));
  }
  return a;
}

// ---------------- prep kernel: weight-side B operands into d_ws ----------------
// wupT[l][d][kk] = w_up[l][kk][d]              (3*128*512 fp16)
// ywT [l][d][n*8+f] = y[n][d]*we_ne[l][f][d]   (3*128*128 fp16), y = embed[atypes]
__global__ void gnn_prep(const float* __restrict__ w_up, const float* __restrict__ we_ne,
                         const float* __restrict__ embed, const int* __restrict__ atypes,
                         u16* __restrict__ wupT, u16* __restrict__ ywT){
  int id = blockIdx.x * 256 + threadIdx.x;
  if (id < 3*512*128){
    int kk = id & 511, d = (id >> 9) & 127, l = id >> 16;
    wupT[(l*128 + d)*512 + kk] = f2h(w_up[(l*512 + kk)*128 + d]);
  } else {
    id -= 3*512*128;
    int k = id & 127, d = (id >> 7) & 127, l = id >> 14;
    int n = k >> 3, f = k & 7;
    float y  = embed[atypes[n]*128 + d];
    float wn = we_ne[(l*8 + f)*128 + d];
    ywT[(l*128 + d)*128 + k] = f2h(y * wn);
  }
}

// ---------------- main kernel ----------------
__global__ __launch_bounds__(256, 2) void gnn_main(
    const float* __restrict__ r_g, const float* __restrict__ R_g,
    const float* __restrict__ weS_g, const float* __restrict__ weA_g,
    const float* __restrict__ bup_g,
    const u16* __restrict__ wupT, const u16* __restrict__ ywT,
    float* __restrict__ out)
{
  __shared__ __attribute__((aligned(16))) u16 xb[64][136];   // x, fp16, row-major
  __shared__ __attribute__((aligned(16))) u16 zst[64][136];  // z staging (per-wave rows)

  const int tid  = threadIdx.x;
  const int b    = blockIdx.x;
  const int lane = tid & 63;
  const int w    = tid >> 6;          // wave id 0..3
  const int col  = lane & 15;         // MFMA m/n index
  const int q    = lane >> 4;         // MFMA quad
  const int i0   = w * 16;            // this wave's row tile
  const int s    = w >> 1;            // spin block of rows (0: i<32, 1: i>=32)
  const int mrow = i0 + col;          // A-frag row

  // ---------------- Phase A: positions, per-lane distances, x init ----------------
  float dS[8], dA[8], dN[4];
  {
    float* rs = (float*)&zst[0][0];   // [64][4] overlay (dead until first z staging)
    float* Rs = rs + 256;             // [16][4]
    if (tid < 64){
#pragma unroll
      for (int k = 0; k < 3; k++) rs[tid*4+k] = r_g[(b*64+tid)*3 + k];
    } else if (tid < 80){
      int n = tid - 64;
#pragma unroll
      for (int k = 0; k < 3; k++) Rs[n*4+k] = R_g[(b*16+n)*3 + k];
    }
    __syncthreads();
    {
      float x0 = rs[mrow*4], x1 = rs[mrow*4+1], x2 = rs[mrow*4+2];
#pragma unroll
      for (int c = 0; c < 8; c++){
        int j = 32*s + 4*c + q;
        float dx = x0-rs[j*4], dy = x1-rs[j*4+1], dz = x2-rs[j*4+2];
        dS[c] = sqrtf(dx*dx + dy*dy + dz*dz + 1e-12f);
        j = 32*(1-s) + 4*c + q;
        dx = x0-rs[j*4]; dy = x1-rs[j*4+1]; dz = x2-rs[j*4+2];
        dA[c] = sqrtf(dx*dx + dy*dy + dz*dz + 1e-12f);
      }
#pragma unroll
      for (int c = 0; c < 4; c++){
        int n = 4*c + q;
        float dx = x0-Rs[n*4], dy = x1-Rs[n*4+1], dz = x2-Rs[n*4+2];
        dN[c] = sqrtf(dx*dx + dy*dy + dz*dz + 1e-12f);
      }
    }
    { // x init: ne features -> xb
      int i = tid >> 2, nb = (tid & 3)*4;
      float y0 = rs[i*4], y1 = rs[i*4+1], y2 = rs[i*4+2];
#pragma unroll
      for (int nn = 0; nn < 4; nn++){
        int n = nb + nn;
        float dx = y0-Rs[n*4], dy = y1-Rs[n*4+1], dz = y2-Rs[n*4+2];
        float dd = sqrtf(dx*dx + dy*dy + dz*dz + 1e-12f);
        *(short8*)&xb[i][n*8] = rbf8(dd);
      }
    }
    __syncthreads();
  }

  // x residual fp32, C-layout: rows i0+q*4+rr, col nt*16+col
  f32x4 xr[8];
#pragma unroll
  for (int nt = 0; nt < 8; nt++)
#pragma unroll
    for (int rr = 0; rr < 4; rr++)
      xr[nt][rr] = h2f(xb[i0 + q*4 + rr][nt*16 + col]);

  const f32x4 vzero = {0.f, 0.f, 0.f, 0.f};

#pragma unroll 1
  for (int l = 0; l < 3; l++){
    const u16* wT_l  = wupT + (l*128)*512;
    const u16* ywT_l = ywT  + (l*128)*128;

    float bupr[8];
#pragma unroll
    for (int nt = 0; nt < 8; nt++) bupr[nt] = bup_g[l*128 + nt*16 + col];

    f32x4 upd[8];
#pragma unroll
    for (int nt = 0; nt < 8; nt++) upd[nt] = vzero;

    // ---------- x @ W0 (B-frags direct from global, no barriers) ----------
#pragma unroll
    for (int c = 0; c < 4; c++){
      short8 a = *(const short8*)&xb[mrow][32*c + (q<<3)];
#pragma unroll
      for (int nt = 0; nt < 8; nt++){
        short8 bb = *(const short8*)(wT_l + (nt*16+col)*512 + 32*c + (q<<3));
        upd[nt] = __builtin_amdgcn_mfma_f32_16x16x32_f16(a, bb, upd[nt], 0, 0, 0);
      }
    }

    // ---------- z_same then z_anti (per-lane B-frag recompute, no barriers) ----------
#pragma unroll 1
    for (int pass = 0; pass < 2; pass++){
      const float* weX = pass ? weA_g : weS_g;
      const int jb0 = pass ? 32*(1-s) : 32*s;
      h2 wp[8][4];
#pragma unroll
      for (int nt = 0; nt < 8; nt++)
#pragma unroll
        for (int p = 0; p < 4; p++){
          h2 t;
          t[0] = (_Float16)weX[(l*8 + 2*p  )*128 + nt*16 + col];
          t[1] = (_Float16)weX[(l*8 + 2*p+1)*128 + nt*16 + col];
          wp[nt][p] = t;
        }
      f32x4 zacc[8];
#pragma unroll
      for (int nt = 0; nt < 8; nt++) zacc[nt] = vzero;
#pragma unroll
      for (int c = 0; c < 8; c++){
        int j = jb0 + 4*c + q;
        float dd = pass ? dA[c] : dS[c];
        short8 a = rbf8(dd);
        if (!pass && j == mrow) a = (short8)0;   // no self-interaction
#pragma unroll
        for (int nt = 0; nt < 8; nt++){
          _Float16 xh = __builtin_bit_cast(_Float16, xb[j][nt*16 + col]);
          h2 xd; xd[0] = xh; xd[1] = xh;
          u32x4 bu;
#pragma unroll
          for (int p = 0; p < 4; p++)
            bu[p] = __builtin_bit_cast(u32, (h2)(xd * wp[nt][p]));
          short8 bb = __builtin_bit_cast(short8, bu);
          zacc[nt] = __builtin_amdgcn_mfma_f32_16x16x32_f16(a, bb, zacc[nt], 0, 0, 0);
        }
      }
      // stage z (own rows only -> no barrier), then z @ W_{1 or 2}
#pragma unroll
      for (int nt = 0; nt < 8; nt++)
#pragma unroll
        for (int rr = 0; rr < 4; rr++)
          zst[i0 + q*4 + rr][nt*16 + col] = f2h(zacc[nt][rr]);
      const int kb0 = pass ? 256 : 128;
#pragma unroll
      for (int c = 0; c < 4; c++){
        short8 a = *(const short8*)&zst[mrow][32*c + (q<<3)];
#pragma unroll
        for (int nt = 0; nt < 8; nt++){
          short8 bb = *(const short8*)(wT_l + (nt*16+col)*512 + kb0 + 32*c + (q<<3));
          upd[nt] = __builtin_amdgcn_mfma_f32_16x16x32_f16(a, bb, upd[nt], 0, 0, 0);
        }
      }
    }

    // ---------- z_ne (B-frags direct from global ywT, no barriers) ----------
    {
      f32x4 zacc[8];
#pragma unroll
      for (int nt = 0; nt < 8; nt++) zacc[nt] = vzero;
#pragma unroll
      for (int c = 0; c < 4; c++){
        short8 a = rbf8(dN[c]);
#pragma unroll
        for (int nt = 0; nt < 8; nt++){
          short8 bb = *(const short8*)(ywT_l + (nt*16+col)*128 + 32*c + (q<<3));
          zacc[nt] = __builtin_amdgcn_mfma_f32_16x16x32_f16(a, bb, zacc[nt], 0, 0, 0);
        }
      }
#pragma unroll
      for (int nt = 0; nt < 8; nt++)
#pragma unroll
        for (int rr = 0; rr < 4; rr++)
          zst[i0 + q*4 + rr][nt*16 + col] = f2h(zacc[nt][rr]);
#pragma unroll
      for (int c = 0; c < 4; c++){
        short8 a = *(const short8*)&zst[mrow][32*c + (q<<3)];
#pragma unroll
        for (int nt = 0; nt < 8; nt++){
          short8 bb = *(const short8*)(wT_l + (nt*16+col)*512 + 384 + 32*c + (q<<3));
          upd[nt] = __builtin_amdgcn_mfma_f32_16x16x32_f16(a, bb, upd[nt], 0, 0, 0);
        }
      }
    }

    // ---------- epilogue: x += tanh(upd + b) ----------
#pragma unroll
    for (int nt = 0; nt < 8; nt++){
#pragma unroll
      for (int rr = 0; rr < 4; rr++){
        float v = upd[nt][rr] + bupr[nt];
        float e = __expf(2.0f * v);
        float th = 1.0f - 2.0f * __builtin_amdgcn_rcpf(e + 1.0f);
        xr[nt][rr] += th;
      }
    }
    if (l < 2){
      __syncthreads();   // all xb reads of this layer done
#pragma unroll
      for (int nt = 0; nt < 8; nt++)
#pragma unroll
        for (int rr = 0; rr < 4; rr++)
          xb[i0 + q*4 + rr][nt*16 + col] = f2h(xr[nt][rr]);
      __syncthreads();   // new xb visible to all
    } else {
#pragma unroll
      for (int nt = 0; nt < 8; nt++)
#pragma unroll
        for (int rr = 0; rr < 4; rr++)
          out[(b*64 + i0 + q*4 + rr)*128 + nt*16 + col] = xr[nt][rr];
    }
  }
}

extern "C" void kernel_launch(void* const* d_in, const int* in_sizes, int n_in,
                              void* d_out, int out_size, void* d_ws, size_t ws_size,
                              hipStream_t stream){
  const float* r     = (const float*)d_in[0];
  const float* R     = (const float*)d_in[1];
  const float* embed = (const float*)d_in[2];
  const float* weS   = (const float*)d_in[3];
  const float* weA   = (const float*)d_in[4];
  const float* weN   = (const float*)d_in[5];
  const float* wup   = (const float*)d_in[6];
  const float* bup   = (const float*)d_in[7];
  const int* atyp    = (const int*)d_in[8];

  u16* wupT = (u16*)d_ws;                 // 3*128*512 fp16 = 393216 B
  u16* ywT  = wupT + 3*128*512;           // 3*128*128 fp16 =  98304 B

  gnn_prep<<<960, 256, 0, stream>>>(wup, weN, embed, atyp, wupT, ywT);
  gnn_main<<<512, 256, 0, stream>>>(r, R, weS, weA, bup, wupT, ywT, (float*)d_out);
}

// Round 7
// 137.036 us; speedup vs baseline: 1.7220x; 1.7220x over previous
//
#include <hip/hip_runtime.h>

// ElectronGNN on MI355X (gfx950).  Inputs float32, output float32.
// 512 blocks (one per batch), 256 threads = 4 waves, LDS 51,200 B.
// All contractions on v_mfma_f32_16x16x32_f16, fp32 accum.
// Weight B-operands: prep writes frag-linear slabs (lane*16B order, coalesced
// via LDS transpose); main runs a 20-phase/layer quarter-slab (8 KB) ping-pong
// pipeline: stage quarter t+1 (global dwordx4 -> regs -> ds_write_b128) while
// consuming quarter t (8 MFMAs), one barrier per phase.
// z B-frags: per-lane v_pk_mul_f16 recompute from xb (LDS) * we (global f32,
// r4-proven path).  z C->A transpose via wave-private zst rows.
// d_ws usage: 491,520 B exactly (r3/r4-proven size; round-5/6's extra wefT
// table pushed past it and read back poison — the deterministic 5.84 failure).

typedef unsigned short u16;
typedef unsigned int u32;
typedef __attribute__((ext_vector_type(8))) short short8;
typedef __attribute__((ext_vector_type(4))) float f32x4;
typedef __attribute__((ext_vector_type(4))) u32 u32x4;
typedef _Float16 h2 __attribute__((ext_vector_type(2)));

__device__ __forceinline__ u16 f2h(float f){ return __builtin_bit_cast(u16, (_Float16)f); }
__device__ __forceinline__ float h2f(u16 a){ return (float)__builtin_bit_cast(_Float16, a); }

__device__ __forceinline__ short8 rbf8(float dd){
  short8 a;
#pragma unroll
  for (int f = 0; f < 8; f++){
    float u = dd - (4.0f/7.0f)*(float)f;
    a[f] = (short)f2h(__expf(-u*u));
  }
  return a;
}

// ---------------- prep: frag-linear weight slabs (coalesced) ----------------
// One block per (l,seg), 15 blocks.  seg 0..3: w_up rows seg*128..+127 of
// layer l; seg 4: ywT[k=n*8+f][d] = embed[atypes[n]][d]*we_ne[l][f][d].
// Stage the 128x128 slab k-major in LDS, then write wsegs linearly:
//   wsegs[blk*16384 + p],  p = slot*512 + lanepos*8 + jj,
//   k = (slot>>3)*32 + (lanepos>>4)*8 + jj, dout = (slot&7)*16 + (lanepos&15)
__global__ __launch_bounds__(256) void gnn_prep(
    const float* __restrict__ w_up, const float* __restrict__ we_ne,
    const float* __restrict__ embed, const int* __restrict__ atypes,
    u16* __restrict__ wsegs){
  __shared__ u16 lw[16384];            // [k][dout] k-major, 32 KB
  const int blk = blockIdx.x;          // l*5 + seg
  const int l = blk / 5, seg = blk % 5;
  const int tid = threadIdx.x;
  if (seg < 4){
    const float* src = w_up + (l*512 + seg*128)*128;
#pragma unroll
    for (int mm = 0; mm < 16; mm++){
      int idx = mm*1024 + tid*4;       // k*128 + dout
      float4 v = *(const float4*)(src + idx);
      lw[idx+0] = f2h(v.x); lw[idx+1] = f2h(v.y);
      lw[idx+2] = f2h(v.z); lw[idx+3] = f2h(v.w);
    }
  } else {
#pragma unroll
    for (int mm = 0; mm < 16; mm++){
      int idx = mm*1024 + tid*4;
      int k = idx >> 7, dout = idx & 127;
      int n = k >> 3, f = k & 7;
      float4 ye = *(const float4*)(embed + atypes[n]*128 + dout);
      float4 wn = *(const float4*)(we_ne + (l*8 + f)*128 + dout);
      lw[idx+0] = f2h(ye.x*wn.x); lw[idx+1] = f2h(ye.y*wn.y);
      lw[idx+2] = f2h(ye.z*wn.z); lw[idx+3] = f2h(ye.w*wn.w);
    }
  }
  __syncthreads();
  u16* dst = wsegs + blk*16384;
  const int col = tid & 15, q = (tid >> 4) & 3;
#pragma unroll
  for (int m = 0; m < 8; m++){
    int slot = m*4 + (tid >> 6);
    int c = slot >> 3, nt = slot & 7;
    int kbase = c*32 + q*8;
    int dout = nt*16 + col;
    short8 vv;
#pragma unroll
    for (int jj = 0; jj < 8; jj++) vv[jj] = (short)lw[(kbase+jj)*128 + dout];
    *(short8*)(dst + m*2048 + tid*8) = vv;   // linear, fully coalesced
  }
}

// ---------------- main ----------------
__global__ __launch_bounds__(256, 2) void gnn_main(
    const float* __restrict__ r_g, const float* __restrict__ R_g,
    const float* __restrict__ weS_g, const float* __restrict__ weA_g,
    const float* __restrict__ bup_g,
    const u16* __restrict__ wsegs,
    float* __restrict__ out)
{
  __shared__ __attribute__((aligned(16))) u16 xb[64][136];     // 17408 B
  __shared__ __attribute__((aligned(16))) u16 zst[64][136];    // 17408 B
  __shared__ __attribute__((aligned(16))) u16 wbuf[2][4096];   // 2 x 8 KB quarters

  const int tid  = threadIdx.x;
  const int b    = blockIdx.x;
  const int lane = tid & 63;
  const int w    = tid >> 6;
  const int col  = lane & 15;
  const int q    = lane >> 4;
  const int i0   = w * 16;
  const int s    = w >> 1;
  const int mrow = i0 + col;
  const int loff = (q*16 + col) * 8;     // B-frag offset within 1KB chunk (u16)

  u32x4 stg[2];
  auto stg_ld = [&](const u16* src){
#pragma unroll
    for (int m = 0; m < 2; m++) stg[m] = *(const u32x4*)(src + m*2048 + tid*8);
  };
  auto stg_st = [&](u16* dst){
#pragma unroll
    for (int m = 0; m < 2; m++) *(u32x4*)(dst + m*2048 + tid*8) = stg[m];
  };
  auto gemm_q = [&](const u16* wb, short8 a, f32x4* acc){
#pragma unroll
    for (int nt = 0; nt < 8; nt++){
      short8 bb = *(const short8*)(wb + nt*512 + loff);
      acc[nt] = __builtin_amdgcn_mfma_f32_16x16x32_f16(a, bb, acc[nt], 0, 0, 0);
    }
  };

  // ---------------- Phase A0: positions, distances, x init, stage W0q0 ----------------
  float dS[8], dA[8], dN[4];
  {
    float* rs = (float*)&zst[0][0];    // overlay (dead until zpass(0))
    float* Rs = rs + 256;
    if (tid < 64){
#pragma unroll
      for (int k = 0; k < 3; k++) rs[tid*4+k] = r_g[(b*64+tid)*3 + k];
    } else if (tid < 80){
      int n = tid - 64;
#pragma unroll
      for (int k = 0; k < 3; k++) Rs[n*4+k] = R_g[(b*16+n)*3 + k];
    }
    __syncthreads();
    {
      float x0 = rs[mrow*4], x1 = rs[mrow*4+1], x2 = rs[mrow*4+2];
#pragma unroll
      for (int c = 0; c < 8; c++){
        int j = 32*s + 4*c + q;
        float dx = x0-rs[j*4], dy = x1-rs[j*4+1], dz = x2-rs[j*4+2];
        dS[c] = sqrtf(dx*dx + dy*dy + dz*dz + 1e-12f);
        j = 32*(1-s) + 4*c + q;
        dx = x0-rs[j*4]; dy = x1-rs[j*4+1]; dz = x2-rs[j*4+2];
        dA[c] = sqrtf(dx*dx + dy*dy + dz*dz + 1e-12f);
      }
#pragma unroll
      for (int c = 0; c < 4; c++){
        int n = 4*c + q;
        float dx = x0-Rs[n*4], dy = x1-Rs[n*4+1], dz = x2-Rs[n*4+2];
        dN[c] = sqrtf(dx*dx + dy*dy + dz*dz + 1e-12f);
      }
    }
    {
      int i = tid >> 2, nb = (tid & 3)*4;
      float y0 = rs[i*4], y1 = rs[i*4+1], y2 = rs[i*4+2];
#pragma unroll
      for (int nn = 0; nn < 4; nn++){
        int n = nb + nn;
        float dx = y0-Rs[n*4], dy = y1-Rs[n*4+1], dz = y2-Rs[n*4+2];
        float dd = sqrtf(dx*dx + dy*dy + dz*dz + 1e-12f);
        *(short8*)&xb[i][n*8] = rbf8(dd);
      }
    }
    stg_ld(wsegs + 0);            // W0q0 of layer 0
    stg_st(wbuf[0]);
    __syncthreads();
  }

  f32x4 xr[8];
#pragma unroll
  for (int nt = 0; nt < 8; nt++)
#pragma unroll
    for (int rr = 0; rr < 4; rr++)
      xr[nt][rr] = h2f(xb[i0 + q*4 + rr][nt*16 + col]);

  const f32x4 vzero = {0.f, 0.f, 0.f, 0.f};

#pragma unroll 1
  for (int l = 0; l < 3; l++){
    const u16* slab = wsegs + l*81920;           // 5 segs x 16384
    float bupr[8];
#pragma unroll
    for (int nt = 0; nt < 8; nt++) bupr[nt] = bup_g[l*128 + nt*16 + col];

    f32x4 upd[8], zn[8];
#pragma unroll
    for (int nt = 0; nt < 8; nt++){ upd[nt] = vzero; zn[nt] = vzero; }

    // z-pass: weights straight from global f32 (r4-proven path)
    auto zpass = [&](int pass){
      const float* weX = pass ? weA_g : weS_g;
      const int jb0 = pass ? 32*(1-s) : 32*s;
      const float* dX = pass ? dA : dS;
      h2 wp[8][4];
#pragma unroll
      for (int nt = 0; nt < 8; nt++)
#pragma unroll
        for (int p = 0; p < 4; p++){
          h2 t;
          t[0] = (_Float16)weX[(l*8 + 2*p  )*128 + nt*16 + col];
          t[1] = (_Float16)weX[(l*8 + 2*p+1)*128 + nt*16 + col];
          wp[nt][p] = t;
        }
      short8 aF[8];
#pragma unroll
      for (int c = 0; c < 8; c++){
        aF[c] = rbf8(dX[c]);
        if (!pass && (jb0 + 4*c + q == mrow)) aF[c] = (short8)0;
      }
      f32x4 zacc[8];
#pragma unroll
      for (int nt = 0; nt < 8; nt++) zacc[nt] = vzero;
#pragma unroll
      for (int nt = 0; nt < 8; nt++){
        u16 xv[8];
#pragma unroll
        for (int c = 0; c < 8; c++) xv[c] = xb[jb0 + 4*c + q][nt*16 + col];
#pragma unroll
        for (int c = 0; c < 8; c++){
          _Float16 xh = __builtin_bit_cast(_Float16, xv[c]);
          h2 xd; xd[0] = xh; xd[1] = xh;
          u32x4 bu;
#pragma unroll
          for (int p = 0; p < 4; p++)
            bu[p] = __builtin_bit_cast(u32, (h2)(xd * wp[nt][p]));
          short8 bb = __builtin_bit_cast(short8, bu);
          zacc[nt] = __builtin_amdgcn_mfma_f32_16x16x32_f16(aF[c], bb, zacc[nt], 0, 0, 0);
        }
      }
#pragma unroll
      for (int nt = 0; nt < 8; nt++)
#pragma unroll
        for (int rr = 0; rr < 4; rr++)
          zst[i0 + q*4 + rr][nt*16 + col] = f2h(zacc[nt][rr]);
    };

    auto A_xb  = [&](int c){ return *(const short8*)&xb [mrow][c*32 + (q<<3)]; };
    auto A_zst = [&](int c){ return *(const short8*)&zst[mrow][c*32 + (q<<3)]; };
    const u16* const sl = slab;
#define QP(seg,c) (sl + (seg)*16384 + (c)*4096)
#define PHASE(nxt, pc, afrag, acc) \
    { stg_ld(nxt); gemm_q(wbuf[pc], (afrag), (acc)); stg_st(wbuf[1-(pc)]); __syncthreads(); }

    // t0: consume W0q0 | zpass(0) | stage W0q1
    stg_ld(QP(0,1)); zpass(0);
    gemm_q(wbuf[0], A_xb(0), upd);
    stg_st(wbuf[1]); __syncthreads();
    PHASE(QP(0,2), 1, A_xb(1), upd)           // t1
    PHASE(QP(0,3), 0, A_xb(2), upd)           // t2
    PHASE(QP(1,0), 1, A_xb(3), upd)           // t3
    PHASE(QP(1,1), 0, A_zst(0), upd)          // t4  (zs)
    PHASE(QP(1,2), 1, A_zst(1), upd)          // t5
    PHASE(QP(1,3), 0, A_zst(2), upd)          // t6
    // t7: consume W1q3 | zpass(1) overwrites zst (after A-frag read) | stage W2q0
    stg_ld(QP(2,0));
    gemm_q(wbuf[1], A_zst(3), upd);
    zpass(1);
    stg_st(wbuf[0]); __syncthreads();
    PHASE(QP(2,1), 0, A_zst(0), upd)          // t8  (za)
    PHASE(QP(2,2), 1, A_zst(1), upd)          // t9
    PHASE(QP(2,3), 0, A_zst(2), upd)          // t10
    PHASE(QP(4,0), 1, A_zst(3), upd)          // t11
    PHASE(QP(4,1), 0, rbf8(dN[0]), zn)        // t12 (Y)
    PHASE(QP(4,2), 1, rbf8(dN[1]), zn)        // t13
    PHASE(QP(4,3), 0, rbf8(dN[2]), zn)        // t14
    // t15: consume Yq3 | write zn->zst | stage W3q0
    stg_ld(QP(3,0));
    gemm_q(wbuf[1], rbf8(dN[3]), zn);
#pragma unroll
    for (int nt = 0; nt < 8; nt++)
#pragma unroll
      for (int rr = 0; rr < 4; rr++)
        zst[i0 + q*4 + rr][nt*16 + col] = f2h(zn[nt][rr]);
    stg_st(wbuf[0]); __syncthreads();
    PHASE(QP(3,1), 0, A_zst(0), upd)          // t16 (zn)
    PHASE(QP(3,2), 1, A_zst(1), upd)          // t17
    PHASE(QP(3,3), 0, A_zst(2), upd)          // t18
    // t19: consume W3q3 | prefetch next layer W0q0 | epilogue
    if (l < 2) stg_ld(sl + 81920);
    gemm_q(wbuf[1], A_zst(3), upd);
#pragma unroll
    for (int nt = 0; nt < 8; nt++){
#pragma unroll
      for (int rr = 0; rr < 4; rr++){
        float v = upd[nt][rr] + bupr[nt];
        float e = __expf(2.0f * v);
        float th = 1.0f - 2.0f * __builtin_amdgcn_rcpf(e + 1.0f);
        xr[nt][rr] += th;
      }
    }
    if (l < 2){
      stg_st(wbuf[0]);
#pragma unroll
      for (int nt = 0; nt < 8; nt++)
#pragma unroll
        for (int rr = 0; rr < 4; rr++)
          xb[i0 + q*4 + rr][nt*16 + col] = f2h(xr[nt][rr]);
      __syncthreads();
    } else {
#pragma unroll
      for (int nt = 0; nt < 8; nt++)
#pragma unroll
        for (int rr = 0; rr < 4; rr++)
          out[(b*64 + i0 + q*4 + rr)*128 + nt*16 + col] = xr[nt][rr];
    }
#undef QP
#undef PHASE
  }
}

extern "C" void kernel_launch(void* const* d_in, const int* in_sizes, int n_in,
                              void* d_out, int out_size, void* d_ws, size_t ws_size,
                              hipStream_t stream){
  const float* r     = (const float*)d_in[0];
  const float* R     = (const float*)d_in[1];
  const float* embed = (const float*)d_in[2];
  const float* weS   = (const float*)d_in[3];
  const float* weA   = (const float*)d_in[4];
  const float* weN   = (const float*)d_in[5];
  const float* wup   = (const float*)d_in[6];
  const float* bup   = (const float*)d_in[7];
  const int* atyp    = (const int*)d_in[8];

  u16* wsegs = (u16*)d_ws;                // 3*5*16384 fp16 = 491,520 B (proven size)

  gnn_prep<<<15, 256, 0, stream>>>(wup, weN, embed, atyp, wsegs);
  gnn_main<<<512, 256, 0, stream>>>(r, R, weS, weA, bup, wsegs, (float*)d_out);
}

// Round 8
// 136.363 us; speedup vs baseline: 1.7304x; 1.0049x over previous
//
#include <hip/hip_runtime.h>

// ElectronGNN on MI355X (gfx950).  Inputs float32, output float32.
// Round 8: weights-LDS-resident design.
//   256 blocks x 512 threads (8 waves), 2 batches/block, 1 block/CU.
//   Dynamic LDS 135,168 B: 2x32KB weight ping-pong + xb/zst per batch.
//   5 phases per layer (W0,W1,W2,Y,W3): stage seg t+1 (coalesced dwordx4 ->
//   regs -> ds_write_b128) while consuming seg t (32 MFMAs + zpass work).
//   16 barriers total (was 61).  rbf8 ee-A-frags cached across layers (64 VGPRs).
// z B-frags: per-lane v_pk_mul_f16 recompute (r4/r7-proven).  zst wave-private.
// d_ws: 491,520 B (r7-proven size, unchanged).

typedef unsigned short u16;
typedef unsigned int u32;
typedef __attribute__((ext_vector_type(8))) short short8;
typedef __attribute__((ext_vector_type(4))) float f32x4;
typedef __attribute__((ext_vector_type(4))) u32 u32x4;
typedef _Float16 h2 __attribute__((ext_vector_type(2)));

__device__ __forceinline__ u16 f2h(float f){ return __builtin_bit_cast(u16, (_Float16)f); }
__device__ __forceinline__ float h2f(u16 a){ return (float)__builtin_bit_cast(_Float16, a); }

__device__ __forceinline__ short8 rbf8(float dd){
  short8 a;
#pragma unroll
  for (int f = 0; f < 8; f++){
    float u = dd - (4.0f/7.0f)*(float)f;
    a[f] = (short)f2h(__expf(-u*u));
  }
  return a;
}

// ---------------- prep: frag-linear weight slabs (r7-proven, unchanged) ----------------
__global__ __launch_bounds__(256) void gnn_prep(
    const float* __restrict__ w_up, const float* __restrict__ we_ne,
    const float* __restrict__ embed, const int* __restrict__ atypes,
    u16* __restrict__ wsegs){
  __shared__ u16 lw[16384];
  const int blk = blockIdx.x;          // l*5 + seg
  const int l = blk / 5, seg = blk % 5;
  const int tid = threadIdx.x;
  if (seg < 4){
    const float* src = w_up + (l*512 + seg*128)*128;
#pragma unroll
    for (int mm = 0; mm < 16; mm++){
      int idx = mm*1024 + tid*4;
      float4 v = *(const float4*)(src + idx);
      lw[idx+0] = f2h(v.x); lw[idx+1] = f2h(v.y);
      lw[idx+2] = f2h(v.z); lw[idx+3] = f2h(v.w);
    }
  } else {
#pragma unroll
    for (int mm = 0; mm < 16; mm++){
      int idx = mm*1024 + tid*4;
      int k = idx >> 7, dout = idx & 127;
      int n = k >> 3, f = k & 7;
      float4 ye = *(const float4*)(embed + atypes[n]*128 + dout);
      float4 wn = *(const float4*)(we_ne + (l*8 + f)*128 + dout);
      lw[idx+0] = f2h(ye.x*wn.x); lw[idx+1] = f2h(ye.y*wn.y);
      lw[idx+2] = f2h(ye.z*wn.z); lw[idx+3] = f2h(ye.w*wn.w);
    }
  }
  __syncthreads();
  u16* dst = wsegs + blk*16384;
  const int col = tid & 15, q = (tid >> 4) & 3;
#pragma unroll
  for (int m = 0; m < 8; m++){
    int slot = m*4 + (tid >> 6);
    int c = slot >> 3, nt = slot & 7;
    int kbase = c*32 + q*8;
    int dout = nt*16 + col;
    short8 vv;
#pragma unroll
    for (int jj = 0; jj < 8; jj++) vv[jj] = (short)lw[(kbase+jj)*128 + dout];
    *(short8*)(dst + m*2048 + tid*8) = vv;
  }
}

// ---------------- main ----------------
__global__ __launch_bounds__(512, 2) void gnn_main(
    const float* __restrict__ r_g, const float* __restrict__ R_g,
    const float* __restrict__ weS_g, const float* __restrict__ weA_g,
    const float* __restrict__ bup_g,
    const u16* __restrict__ wsegs,
    float* __restrict__ out)
{
  extern __shared__ __attribute__((aligned(16))) u16 lds[];
  u16* const wb0 = lds;                 // 16384 u16 (32 KB)
  u16* const wb1 = lds + 16384;         // 16384 u16 (32 KB)
  u16* const xbB = lds + 32768;         // 2 x [64][136]
  u16* const zsB = lds + 50176;         // 2 x [64][136]

  const int tid  = threadIdx.x;
  const int lane = tid & 63;
  const int w    = tid >> 6;            // 0..7
  const int bb   = w >> 2;              // batch half 0/1
  const int wq   = w & 3;               // row-tile within batch
  const int b    = blockIdx.x*2 + bb;
  const int col  = lane & 15;
  const int q    = lane >> 4;
  const int i0   = wq * 16;
  const int sp   = wq >> 1;             // spin group of rows
  const int mrow = i0 + col;
  const int loff = (q*16 + col) * 8;

  u16* const xb  = xbB + bb*8704;       // [64][136] for my batch
  u16* const zst = zsB + bb*8704;

  u32x4 stg[4];
  auto stg_ld = [&](const u16* src){
#pragma unroll
    for (int m = 0; m < 4; m++) stg[m] = *(const u32x4*)(src + m*4096 + tid*8);
  };
  auto stg_st = [&](u16* dst){
#pragma unroll
    for (int m = 0; m < 4; m++) *(u32x4*)(dst + m*4096 + tid*8) = stg[m];
  };
  // full-seg GEMM: K=128 (4 chunks), N=128 (8 tiles), A from row-major LDS
  auto gemm_seg = [&](const u16* wbuf, const u16* arows, f32x4* acc){
#pragma unroll
    for (int c = 0; c < 4; c++){
      short8 a = *(const short8*)(arows + mrow*136 + c*32 + (q<<3));
#pragma unroll
      for (int nt = 0; nt < 8; nt++){
        short8 bf = *(const short8*)(wbuf + c*4096 + nt*512 + loff);
        acc[nt] = __builtin_amdgcn_mfma_f32_16x16x32_f16(a, bf, acc[nt], 0, 0, 0);
      }
    }
  };

  // ---------------- init: positions, distances, cached A-frags, x init ----------------
  short8 aS[8], aA[8];
  float dN[4];
  {
    float* rs = (float*)(zsB + bb*8704);     // overlay per batch (dead until zpass)
    float* Rs = rs + 256;
    const int ht = tid & 255;
    if (ht < 64){
#pragma unroll
      for (int k = 0; k < 3; k++) rs[ht*4+k] = r_g[(b*64+ht)*3 + k];
    } else if (ht < 80){
      int n = ht - 64;
#pragma unroll
      for (int k = 0; k < 3; k++) Rs[n*4+k] = R_g[(b*16+n)*3 + k];
    }
    __syncthreads();
    {
      float x0 = rs[mrow*4], x1 = rs[mrow*4+1], x2 = rs[mrow*4+2];
#pragma unroll
      for (int c = 0; c < 8; c++){
        int j = 32*sp + 4*c + q;
        float dx = x0-rs[j*4], dy = x1-rs[j*4+1], dz = x2-rs[j*4+2];
        float dd = sqrtf(dx*dx + dy*dy + dz*dz + 1e-12f);
        aS[c] = rbf8(dd);
        if (j == mrow) aS[c] = (short8)0;          // no self-interaction
        j = 32*(1-sp) + 4*c + q;
        dx = x0-rs[j*4]; dy = x1-rs[j*4+1]; dz = x2-rs[j*4+2];
        aA[c] = rbf8(sqrtf(dx*dx + dy*dy + dz*dz + 1e-12f));
      }
#pragma unroll
      for (int c = 0; c < 4; c++){
        int n = 4*c + q;
        float dx = x0-Rs[n*4], dy = x1-Rs[n*4+1], dz = x2-Rs[n*4+2];
        dN[c] = sqrtf(dx*dx + dy*dy + dz*dz + 1e-12f);
      }
    }
    {
      int i = (tid & 255) >> 2, nb = (tid & 3)*4;
      float y0 = rs[i*4], y1 = rs[i*4+1], y2 = rs[i*4+2];
#pragma unroll
      for (int nn = 0; nn < 4; nn++){
        int n = nb + nn;
        float dx = y0-Rs[n*4], dy = y1-Rs[n*4+1], dz = y2-Rs[n*4+2];
        float dd = sqrtf(dx*dx + dy*dy + dz*dz + 1e-12f);
        *(short8*)&xb[i*136 + n*8] = rbf8(dd);
      }
    }
    stg_ld(wsegs + 0);          // L0.W0 -> wb0
    stg_st(wb0);
    __syncthreads();
  }

  f32x4 xr[8];
#pragma unroll
  for (int nt = 0; nt < 8; nt++)
#pragma unroll
    for (int rr = 0; rr < 4; rr++)
      xr[nt][rr] = h2f(xb[(i0 + q*4 + rr)*136 + nt*16 + col]);

  const f32x4 vzero = {0.f, 0.f, 0.f, 0.f};

#pragma unroll 1
  for (int l = 0; l < 3; l++){
    const u16* slab = wsegs + l*81920;
    const int P = l & 1;
    u16* const bufA = P ? wb1 : wb0;    // holds W0 at layer start
    u16* const bufB = P ? wb0 : wb1;

    float bupr[8];
#pragma unroll
    for (int nt = 0; nt < 8; nt++) bupr[nt] = bup_g[l*128 + nt*16 + col];

    f32x4 upd[8];
#pragma unroll
    for (int nt = 0; nt < 8; nt++) upd[nt] = vzero;

    auto zpass = [&](int pass){
      const float* weX = pass ? weA_g : weS_g;
      const int jb0 = pass ? 32*(1-sp) : 32*sp;
      const short8* aF = pass ? aA : aS;
      f32x4 zacc[8];
#pragma unroll
      for (int nt = 0; nt < 8; nt++) zacc[nt] = vzero;
#pragma unroll
      for (int nt = 0; nt < 8; nt++){
        h2 wp[4];
#pragma unroll
        for (int p = 0; p < 4; p++){
          h2 t;
          t[0] = (_Float16)weX[(l*8 + 2*p  )*128 + nt*16 + col];
          t[1] = (_Float16)weX[(l*8 + 2*p+1)*128 + nt*16 + col];
          wp[p] = t;
        }
        u16 xv[8];
#pragma unroll
        for (int c = 0; c < 8; c++) xv[c] = xb[(jb0 + 4*c + q)*136 + nt*16 + col];
#pragma unroll
        for (int c = 0; c < 8; c++){
          _Float16 xh = __builtin_bit_cast(_Float16, xv[c]);
          h2 xd; xd[0] = xh; xd[1] = xh;
          u32x4 bu;
#pragma unroll
          for (int p = 0; p < 4; p++)
            bu[p] = __builtin_bit_cast(u32, (h2)(xd * wp[p]));
          short8 bf = __builtin_bit_cast(short8, bu);
          zacc[nt] = __builtin_amdgcn_mfma_f32_16x16x32_f16(aF[c], bf, zacc[nt], 0, 0, 0);
        }
      }
#pragma unroll
      for (int nt = 0; nt < 8; nt++)
#pragma unroll
        for (int rr = 0; rr < 4; rr++)
          zst[(i0 + q*4 + rr)*136 + nt*16 + col] = f2h(zacc[nt][rr]);
    };

    // ---- t0: consume W0 (x@W0) + zpass(0) | stage W1 -> bufB
    stg_ld(slab + 1*16384);
    zpass(0);
    gemm_seg(bufA, xb, upd);
    stg_st(bufB); __syncthreads();
    // ---- t1: consume W1 (zs@W1) | stage W2 -> bufA
    stg_ld(slab + 2*16384);
    gemm_seg(bufB, zst, upd);
    stg_st(bufA); __syncthreads();
    // ---- t2: zpass(1) then consume W2 (za@W2) | stage Y -> bufB
    stg_ld(slab + 4*16384);
    zpass(1);
    gemm_seg(bufA, zst, upd);
    stg_st(bufB); __syncthreads();
    // ---- t3: consume Y (zn), write zn->zst | stage W3 -> bufA
    stg_ld(slab + 3*16384);
    {
      f32x4 zn[8];
#pragma unroll
      for (int nt = 0; nt < 8; nt++) zn[nt] = vzero;
#pragma unroll
      for (int c = 0; c < 4; c++){
        short8 a = rbf8(dN[c]);
#pragma unroll
        for (int nt = 0; nt < 8; nt++){
          short8 bf = *(const short8*)(bufB + c*4096 + nt*512 + loff);
          zn[nt] = __builtin_amdgcn_mfma_f32_16x16x32_f16(a, bf, zn[nt], 0, 0, 0);
        }
      }
#pragma unroll
      for (int nt = 0; nt < 8; nt++)
#pragma unroll
        for (int rr = 0; rr < 4; rr++)
          zst[(i0 + q*4 + rr)*136 + nt*16 + col] = f2h(zn[nt][rr]);
    }
    stg_st(bufA); __syncthreads();
    // ---- t4: consume W3 (zn@W3) | stage next-layer W0 -> bufB | epilogue
    if (l < 2) stg_ld(slab + 81920);
    gemm_seg(bufA, zst, upd);
#pragma unroll
    for (int nt = 0; nt < 8; nt++){
#pragma unroll
      for (int rr = 0; rr < 4; rr++){
        float v = upd[nt][rr] + bupr[nt];
        float e = __expf(2.0f * v);
        float th = 1.0f - 2.0f * __builtin_amdgcn_rcpf(e + 1.0f);
        xr[nt][rr] += th;
      }
    }
    if (l < 2){
#pragma unroll
      for (int nt = 0; nt < 8; nt++)
#pragma unroll
        for (int rr = 0; rr < 4; rr++)
          xb[(i0 + q*4 + rr)*136 + nt*16 + col] = f2h(xr[nt][rr]);
      stg_st(bufB);
      __syncthreads();
    } else {
#pragma unroll
      for (int nt = 0; nt < 8; nt++)
#pragma unroll
        for (int rr = 0; rr < 4; rr++)
          out[(b*64 + i0 + q*4 + rr)*128 + nt*16 + col] = xr[nt][rr];
    }
  }
}

extern "C" void kernel_launch(void* const* d_in, const int* in_sizes, int n_in,
                              void* d_out, int out_size, void* d_ws, size_t ws_size,
                              hipStream_t stream){
  const float* r     = (const float*)d_in[0];
  const float* R     = (const float*)d_in[1];
  const float* embed = (const float*)d_in[2];
  const float* weS   = (const float*)d_in[3];
  const float* weA   = (const float*)d_in[4];
  const float* weN   = (const float*)d_in[5];
  const float* wup   = (const float*)d_in[6];
  const float* bup   = (const float*)d_in[7];
  const int* atyp    = (const int*)d_in[8];

  u16* wsegs = (u16*)d_ws;                // 3*5*16384 fp16 = 491,520 B (proven size)

  (void)hipFuncSetAttribute((const void*)gnn_main,
                            hipFuncAttributeMaxDynamicSharedMemorySize, 135168);
  gnn_prep<<<15, 256, 0, stream>>>(wup, weN, embed, atyp, wsegs);
  gnn_main<<<256, 512, 135168, stream>>>(r, R, weS, weA, bup, wsegs, (float*)d_out);
}